// Round 8
// baseline (78.927 us; speedup 1.0000x reference)
//
#include <hip/hip_runtime.h>
#include <cstddef>

// YOLOv3 loss, MI355X. b=32, scales 13/26/52, 3 anchors, 80 classes, 50 boxes.
// Input order (setup_inputs dict order, interleaved per scale):
//   d_in[4k+0]=output_k (b,255,S,S)  d_in[4k+1]=loc_k (b,3,4,S,S)
//   d_in[4k+2]=cls_k (b,3,80,S,S)    d_in[4k+3]=boxes_k (b,50,4)
// ws: 4 doubles {LL, LC, LK, NPOS} @0, partial planes @256:
//   float4 plane[4][NB*52*52*3]  (Z,A2,A1,A0 per cell per channel-quarter)
//
// R7: split-K on the S=52 class reduction. The session's data shows a latency
// wall: VW4 runs have ~1 wave/SIMD, each exposing ~5-20 load-batch latencies
// serially (L3-resident run was NOT faster -> not a BW wall). Fix = 4x more
// waves at UNCHANGED float4 8-deep batching: 4 blocks each reduce 20 of the 80
// class channels -> per-cell partials; a second kernel combines + tail.
// S13/S26 stay monolithic inside launch A (they overlap the partial blocks).

constexpr int NC = 80;
constexpr int NA = 3;
constexpr int NM = 50;
constexpr int NB = 32;

constexpr int S2SS   = 52 * 52;           // 2704
constexpr int S2CELL = NA * S2SS;         // 8112 per image
constexpr int S2TOT  = NB * S2CELL;       // 259584 cells
constexpr size_t PART_OFF = 256;          // byte offset of partials in ws
constexpr size_t WS_NEEDED = PART_OFF + (size_t)4 * S2TOT * 16;

__device__ constexpr float ANCW[3][3] = {{116.f,156.f,373.f},{30.f,62.f,59.f},{10.f,16.f,33.f}};
__device__ constexpr float ANCH[3][3] = {{ 90.f,198.f,326.f},{61.f,45.f,119.f},{13.f,30.f,23.f}};

__device__ __forceinline__ float frcp_(float x) { return __builtin_amdgcn_rcpf(x); }
__device__ __forceinline__ float sigmoidf_(float x) { return frcp_(1.0f + __expf(-x)); }

template <int VW>
__device__ __forceinline__ void loadv(const float* __restrict__ p, float (&d)[VW]) {
    if constexpr (VW == 4) {
        const float4 v = *reinterpret_cast<const float4*>(p);
        d[0] = v.x; d[1] = v.y; d[2] = v.z; d[3] = v.w;
    } else {
        d[0] = p[0];
    }
}

__global__ void init_acc_kernel(double* acc) {
    if (threadIdx.x < 4) acc[threadIdx.x] = 0.0;
}

__global__ void finalize_kernel(const double* __restrict__ acc, float* __restrict__ out) {
    out[0] = (float)(5.0 * (acc[0] + acc[1] + acc[2]) / (double)NB / acc[3]);
}

// ---------------- shared tail: loc + box + IoU + conf + class-assembly -------
template <int SC, int S, int VW, bool COUNT_POS>
__device__ __forceinline__ void tail_and_reduce(
    const float* __restrict__ outp, const float* __restrict__ locp,
    const float4* __restrict__ sbx4, const float* __restrict__ sba,
    double* __restrict__ acc, float red[4][4],
    int b, int a, int rem, bool active,
    float (&Z)[VW], float (&A2)[VW], float (&A1)[VW], float (&A0)[VW])
{
    constexpr int SS = S * S;
    const int tid = threadIdx.x;
    float ll = 0.f, lc = 0.f, lk = 0.f, np = 0.f;

    if (active) {
        const float* op = outp + ((size_t)b * NA + a) * (5 + NC) * SS + rem;
        const float* lp = locp + ((size_t)b * NA + a) * 4 * SS + rem;

        float tx[VW], ty[VW], tw[VW], th[VW], tc[VW];
        float l0[VW], l1[VW], l2[VW], l3[VW];
        loadv<VW>(op + 0 * SS, tx);
        loadv<VW>(op + 1 * SS, ty);
        loadv<VW>(op + 2 * SS, tw);
        loadv<VW>(op + 3 * SS, th);
        loadv<VW>(op + 4 * SS, tc);
        loadv<VW>(lp + 0 * SS, l0);
        loadv<VW>(lp + 1 * SS, l1);
        loadv<VW>(lp + 2 * SS, l2);
        loadv<VW>(lp + 3 * SS, l3);

        const float aw = ANCW[SC][a] * ((float)S / 416.f);
        const float ah = ANCH[SC][a] * ((float)S / 416.f);

        float x1[VW], y1[VW], x2[VW], y2[VW], area[VW], bn[VW], bd[VW];
        bool pos[VW];
        #pragma unroll
        for (int i = 0; i < VW; ++i) {
            pos[i] = A0[i] > 0.f;
            const float d0 = tx[i]-l0[i], d1 = ty[i]-l1[i], d2 = tw[i]-l2[i], d3 = th[i]-l3[i];
            const float lli = d0*d0 + d1*d1 + d2*d2 + d3*d3;
            ll += pos[i] ? lli : 0.f;
            if (COUNT_POS) np += pos[i] ? 1.f : 0.f;

            const int ri = rem + i;
            const int y  = ri / S;
            const int x  = ri - y * S;
            const float sx = sigmoidf_(tx[i]) + (float)x;
            const float sy = sigmoidf_(ty[i]) + (float)y;
            const float bw = __expf(tw[i]) * aw;
            const float bh = __expf(th[i]) * ah;
            x1[i] = sx - bw * 0.5f;  y1[i] = sy - bh * 0.5f;
            x2[i] = sx + bw * 0.5f;  y2[i] = sy + bh * 0.5f;
            area[i] = (x2[i] - x1[i]) * (y2[i] - y1[i]);
            bn[i] = 0.f; bd[i] = 1.f;
        }

        for (int j = 0; j < NM; ++j) {
            const float4 bb = sbx4[j];
            const float ab  = sba[j];
            #pragma unroll
            for (int i = 0; i < VW; ++i) {
                const float iw = fmaxf(fminf(x2[i], bb.z) - fmaxf(x1[i], bb.x), 0.f);
                const float ih = fmaxf(fminf(y2[i], bb.w) - fmaxf(y1[i], bb.y), 0.f);
                const float inter = iw * ih;
                const float uni   = area[i] + ab - inter;
                const bool upd = inter * bd[i] > bn[i] * uni;
                bn[i] = upd ? inter : bn[i];
                bd[i] = upd ? uni   : bd[i];
            }
        }

        #pragma unroll
        for (int i = 0; i < VW; ++i) {
            const float best  = bn[i] * frcp_(bd[i]);
            const float cpred = sigmoidf_(tc[i]);
            const float m2    = pos[i] ? 1.f : 0.01f;
            const float d     = cpred - best;
            lc += m2 * d * d;
            const float invZ = frcp_(Z[i]);
            lk += fmaf(A2[i] * invZ, invZ, fmaf(-2.f * A1[i], invZ, A0[i]));
        }
    }

    for (int off = 32; off > 0; off >>= 1) {
        ll += __shfl_down(ll, off);
        lc += __shfl_down(lc, off);
        lk += __shfl_down(lk, off);
        if (COUNT_POS) np += __shfl_down(np, off);
    }
    const int wave = tid >> 6, lane = tid & 63;
    if (lane == 0) { red[wave][0]=ll; red[wave][1]=lc; red[wave][2]=lk; red[wave][3]=np; }
    __syncthreads();
    if (tid == 0) {
        float s0=0, s1=0, s2=0, s3=0;
        for (int w = 0; w < 4; ++w) { s0+=red[w][0]; s1+=red[w][1]; s2+=red[w][2]; s3+=red[w][3]; }
        atomicAdd(&acc[0], (double)s0);
        atomicAdd(&acc[1], (double)s1);
        atomicAdd(&acc[2], (double)s2);
        if (COUNT_POS) atomicAdd(&acc[3], (double)s3);
    }
}

// --------------- class-channel partial accumulate (NCH channels) -------------
template <int S, int VW, int NCH>
__device__ __forceinline__ void class_partial(
    const float* __restrict__ opc, const float* __restrict__ cpc,
    float (&Z)[VW], float (&A2)[VW], float (&A1)[VW], float (&A0)[VW])
{
    constexpr int SS = S * S;
    #pragma unroll 2
    for (int c0 = 0; c0 < NCH; c0 += 8) {
        constexpr int JW = 8;
        const int jn = (NCH - c0 < 8) ? (NCH - c0) : 8;
        float L[JW][VW], T[JW][VW];
        #pragma unroll
        for (int j = 0; j < JW; ++j)
            if (j < jn) loadv<VW>(opc + (size_t)(c0 + j) * SS, L[j]);
        #pragma unroll
        for (int j = 0; j < JW; ++j)
            if (j < jn) loadv<VW>(cpc + (size_t)(c0 + j) * SS, T[j]);
        #pragma unroll
        for (int j = 0; j < JW; ++j) {
            if (j < jn) {
                #pragma unroll
                for (int i = 0; i < VW; ++i) {
                    const float e = __expf(L[j][i]);
                    const float t = T[j][i];
                    const float u = fmaxf(t, 0.f);
                    const float we = (t > 0.f) ? e : 0.f;
                    Z[i] += e;
                    A2[i] = fmaf(we, e, A2[i]);
                    A1[i] = fmaf(we, t, A1[i]);
                    A0[i] = fmaf(u,  t, A0[i]);
                }
            }
        }
    }
}

// ---------------- monolithic per-scale body (R1-style, best codegen) ---------
template <int SC, int S, int VW, bool COUNT_POS>
__device__ __forceinline__ void process_mono(
    const float* __restrict__ outp, const float* __restrict__ locp,
    const float* __restrict__ clsp, const float* __restrict__ boxp,
    double* __restrict__ acc, int rel)
{
    constexpr int SS = S * S;
    constexpr int CELLS = NA * SS;
    constexpr int CPB = 256 * VW;
    constexpr int BPB = (CELLS + CPB - 1) / CPB;

    const int b   = rel / BPB;
    const int chk = rel % BPB;
    const int tid = threadIdx.x;

    __shared__ float4 sbx4[NM];
    __shared__ float  sba[NM];
    __shared__ float  red[4][4];
    if (tid < NM) {
        const float4 bb = *reinterpret_cast<const float4*>(boxp + (size_t)b * NM * 4 + tid * 4);
        sbx4[tid] = bb;
        sba[tid]  = (bb.z - bb.x) * (bb.w - bb.y);
    }

    const int cell0 = (chk * 256 + tid) * VW;
    const bool active = cell0 < CELLS;
    int a = 0, rem = 0;
    float Z[VW] = {}, A2[VW] = {}, A1[VW] = {}, A0[VW] = {};
    if (active) {
        a   = cell0 / SS;
        rem = cell0 - a * SS;
        const float* opc = outp + (((size_t)b * NA + a) * (5 + NC) + 5) * SS + rem;
        const float* cpc = clsp + ((size_t)b * NA + a) * NC * SS + rem;
        class_partial<S, VW, NC>(opc, cpc, Z, A2, A1, A0);
    }
    __syncthreads();
    tail_and_reduce<SC, S, VW, COUNT_POS>(outp, locp, sbx4, sba, acc, red,
                                          b, a, rem, active, Z, A2, A1, A0);
}

// grid A: [0,64) S13 mono VW1 | [64,128) S26 mono VW4 | [128,1152) S52 partial
constexpr int A_NBLK0 = NB * ((NA*13*13 + 255) / 256);    // 64
constexpr int A_NBLK1 = NB * ((NA*26*26 + 1023) / 1024);  // 64
constexpr int S2_BPB  = (S2CELL + 1023) / 1024;           // 8
constexpr int A_NBLK2 = NB * S2_BPB * 4;                  // 1024
constexpr int A_TOTAL = A_NBLK0 + A_NBLK1 + A_NBLK2;      // 1152

__global__ __launch_bounds__(256) void yolo_A_kernel(
    const float* __restrict__ o0, const float* __restrict__ lo0, const float* __restrict__ c0, const float* __restrict__ bx0,
    const float* __restrict__ o1, const float* __restrict__ lo1, const float* __restrict__ c1, const float* __restrict__ bx1,
    const float* __restrict__ o2, const float* __restrict__ c2,
    double* __restrict__ acc, float4* __restrict__ part)
{
    const int bid = blockIdx.x;
    if (bid < A_NBLK0) {
        process_mono<0, 13, 1, true>(o0, lo0, c0, bx0, acc, bid);
        return;
    }
    if (bid < A_NBLK0 + A_NBLK1) {
        process_mono<1, 26, 4, false>(o1, lo1, c1, bx1, acc, bid - A_NBLK0);
        return;
    }
    // ---- S52 class partials: split = quarter of the 80 channels ----
    const int rel   = bid - A_NBLK0 - A_NBLK1;
    const int split = rel & 3;
    const int r2    = rel >> 2;
    const int b     = r2 / S2_BPB;
    const int chk   = r2 % S2_BPB;
    const int tid   = threadIdx.x;

    const int cell0 = (chk * 256 + tid) * 4;
    if (cell0 >= S2CELL) return;
    const int a   = cell0 / S2SS;
    const int rem = cell0 - a * S2SS;

    const float* opc = o2 + (((size_t)b * NA + a) * (5 + NC) + 5 + split * 20) * S2SS + rem;
    const float* cpc = c2 + (((size_t)b * NA + a) * NC + split * 20) * S2SS + rem;

    float Z[4] = {}, A2[4] = {}, A1[4] = {}, A0[4] = {};
    class_partial<52, 4, 20>(opc, cpc, Z, A2, A1, A0);

    float4* dst = part + (size_t)split * S2TOT + (size_t)b * S2CELL + cell0;
    #pragma unroll
    for (int i = 0; i < 4; ++i)
        dst[i] = make_float4(Z[i], A2[i], A1[i], A0[i]);
}

// grid B: 256 blocks, S52 combine + tail
__global__ __launch_bounds__(256) void yolo_B_kernel(
    const float* __restrict__ o2, const float* __restrict__ lo2, const float* __restrict__ bx2,
    double* __restrict__ acc, const float4* __restrict__ part)
{
    const int rel = blockIdx.x;
    const int b   = rel / S2_BPB;
    const int chk = rel % S2_BPB;
    const int tid = threadIdx.x;

    __shared__ float4 sbx4[NM];
    __shared__ float  sba[NM];
    __shared__ float  red[4][4];
    if (tid < NM) {
        const float4 bb = *reinterpret_cast<const float4*>(bx2 + (size_t)b * NM * 4 + tid * 4);
        sbx4[tid] = bb;
        sba[tid]  = (bb.z - bb.x) * (bb.w - bb.y);
    }

    const int cell0 = (chk * 256 + tid) * 4;
    const bool active = cell0 < S2CELL;
    int a = 0, rem = 0;
    float Z[4] = {}, A2[4] = {}, A1[4] = {}, A0[4] = {};
    if (active) {
        a   = cell0 / S2SS;
        rem = cell0 - a * S2SS;
        const float4* src = part + (size_t)b * S2CELL + cell0;
        #pragma unroll
        for (int s = 0; s < 4; ++s) {
            #pragma unroll
            for (int i = 0; i < 4; ++i) {
                const float4 p = src[(size_t)s * S2TOT + i];
                Z[i]  += p.x;
                A2[i] += p.y;
                A1[i] += p.z;
                A0[i] += p.w;
            }
        }
    }
    __syncthreads();
    tail_and_reduce<2, 52, 4, false>(o2, lo2, sbx4, sba, acc, red,
                                     b, a, rem, active, Z, A2, A1, A0);
}

// ---------------- fallback monolithic (if ws too small) ----------------------
constexpr int M_NBLK0 = NB * ((NA*13*13 + 255) / 256);
constexpr int M_NBLK1 = NB * ((NA*26*26 + 1023) / 1024);
constexpr int M_NBLK2 = NB * ((NA*52*52 + 1023) / 1024);

__global__ __launch_bounds__(256) void yolo_mono_kernel(
    const float* __restrict__ o0, const float* __restrict__ lo0, const float* __restrict__ c0, const float* __restrict__ bx0,
    const float* __restrict__ o1, const float* __restrict__ lo1, const float* __restrict__ c1, const float* __restrict__ bx1,
    const float* __restrict__ o2, const float* __restrict__ lo2, const float* __restrict__ c2, const float* __restrict__ bx2,
    double* __restrict__ acc)
{
    const int bid = blockIdx.x;
    if (bid < M_NBLK0) {
        process_mono<0, 13, 1, true>(o0, lo0, c0, bx0, acc, bid);
    } else if (bid < M_NBLK0 + M_NBLK1) {
        process_mono<1, 26, 4, false>(o1, lo1, c1, bx1, acc, bid - M_NBLK0);
    } else {
        process_mono<2, 52, 4, false>(o2, lo2, c2, bx2, acc, bid - M_NBLK0 - M_NBLK1);
    }
}

extern "C" void kernel_launch(void* const* d_in, const int* in_sizes, int n_in,
                              void* d_out, int out_size, void* d_ws, size_t ws_size,
                              hipStream_t stream) {
    (void)in_sizes; (void)n_in; (void)out_size;
    const float* o0  = (const float*)d_in[0];
    const float* lo0 = (const float*)d_in[1];
    const float* c0  = (const float*)d_in[2];
    const float* bx0 = (const float*)d_in[3];
    const float* o1  = (const float*)d_in[4];
    const float* lo1 = (const float*)d_in[5];
    const float* c1  = (const float*)d_in[6];
    const float* bx1 = (const float*)d_in[7];
    const float* o2  = (const float*)d_in[8];
    const float* lo2 = (const float*)d_in[9];
    const float* c2  = (const float*)d_in[10];
    const float* bx2 = (const float*)d_in[11];

    double* acc = (double*)d_ws;
    float*  out = (float*)d_out;

    init_acc_kernel<<<1, 64, 0, stream>>>(acc);

    if (ws_size >= WS_NEEDED) {
        float4* part = (float4*)((char*)d_ws + PART_OFF);
        yolo_A_kernel<<<A_TOTAL, 256, 0, stream>>>(
            o0, lo0, c0, bx0, o1, lo1, c1, bx1, o2, c2, acc, part);
        yolo_B_kernel<<<NB * S2_BPB, 256, 0, stream>>>(o2, lo2, bx2, acc, part);
    } else {
        yolo_mono_kernel<<<M_NBLK0 + M_NBLK1 + M_NBLK2, 256, 0, stream>>>(
            o0, lo0, c0, bx0, o1, lo1, c1, bx1, o2, lo2, c2, bx2, acc);
    }

    finalize_kernel<<<1, 1, 0, stream>>>(acc, out);
}